// Round 9
// baseline (422.477 us; speedup 1.0000x reference)
//
#include <hip/hip_runtime.h>
#include <hip/hip_bf16.h>

typedef __attribute__((ext_vector_type(8))) short short8;
typedef __attribute__((ext_vector_type(4))) float float4v;

#define LQ 512
#define NB 4
#define LKV 4096
#define E 256
#define NH 8
#define HD 32
#define NLAYER 4
#define QSCALE 0.17677669529663687f
#define SPLITS 8
#define KSPAN (LKV / SPLITS)
#define QT 128   // q rows per attn block
#define CK 128   // keys per attn chunk

// drain wave's LDS queue + forbid compiler reordering of LDS ops across this point.
// REQUIRED around wave-private cross-lane LDS reuse (myPT). [R6 post-timing race]
#define LDS_FENCE() asm volatile("s_waitcnt lgkmcnt(0)" ::: "memory")

__device__ __forceinline__ unsigned short f2bf(float f) {
    union { float f; unsigned int i; } x; x.f = f;
    unsigned int r = x.i + 0x7fffu + ((x.i >> 16) & 1u);
    return (unsigned short)(r >> 16);
}
__device__ __forceinline__ unsigned int pack2(float a, float b) {
    union { float f; unsigned int i; } xa, xb; xa.f = a; xb.f = b;
    unsigned int ra = xa.i + 0x7fffu + ((xa.i >> 16) & 1u);
    unsigned int rb = xb.i + 0x7fffu + ((xb.i >> 16) & 1u);
    return (ra >> 16) | (rb & 0xffff0000u);
}
__device__ __forceinline__ unsigned int pack2_rtz(float a, float b) {
    union { float f; unsigned int i; } xa, xb; xa.f = a; xb.f = b;
    return __builtin_amdgcn_perm(xb.i, xa.i, 0x07060302u);
}
__device__ __forceinline__ float bf2f(unsigned short u) {
    union { unsigned int i; float f; } x; x.i = ((unsigned int)u) << 16; return x.f;
}
__device__ __forceinline__ float4v mfma16(short8 a, short8 b, float4v c) {
    return __builtin_amdgcn_mfma_f32_16x16x32_bf16(a, b, c, 0, 0, 0);
}
__device__ __forceinline__ void pack_store8(const float* __restrict__ src,
                                            unsigned short* __restrict__ dst) {
    float4 a = *(const float4*)src;
    float4 b = *(const float4*)(src + 4);
    uint4 v;
    v.x = pack2(a.x, a.y); v.y = pack2(a.z, a.w);
    v.z = pack2(b.x, b.y); v.w = pack2(b.z, b.w);
    *(uint4*)dst = v;
}

// ================ one mega pre-pass: all packs + val b-major transpose + init ================
__global__ void pack_all(const float* __restrict__ value, const float* __restrict__ Wqkv,
                         const float* __restrict__ Wo, const float* __restrict__ W1,
                         const float* __restrict__ W2, const float* __restrict__ qpos,
                         const float* __restrict__ vpos, const float* __restrict__ query,
                         unsigned short* __restrict__ val_t, unsigned short* __restrict__ wqkv_bf,
                         unsigned short* __restrict__ wo_bf, unsigned short* __restrict__ w1_bf,
                         unsigned short* __restrict__ w2_bf, unsigned short* __restrict__ qpos_bf,
                         unsigned short* __restrict__ vpos_bf, float* __restrict__ cur,
                         unsigned short* __restrict__ cur_bf) {
    int bid = blockIdx.x;
    if (bid < 2048) {  // value -> val_t [b][seq][E] bf16
        long idx = ((long)bid * 256 + threadIdx.x) * 8;
        int ro = (int)(idx >> 8), e = (int)(idx & 255);
        int ri = ((ro & 4095) << 2) | (ro >> 12);   // in-row = seq*4 + b
        pack_store8(value + (long)ri * 256 + e, val_t + idx);
        return;
    }
    bid -= 2048;
    if (bid < 384) { long i = ((long)bid * 256 + threadIdx.x) * 8; pack_store8(Wqkv + i, wqkv_bf + i); return; }
    bid -= 384;
    if (bid < 128) { long i = ((long)bid * 256 + threadIdx.x) * 8; pack_store8(Wo + i, wo_bf + i); return; }
    bid -= 128;
    if (bid < 128) { long i = ((long)bid * 256 + threadIdx.x) * 8; pack_store8(W1 + i, w1_bf + i); return; }
    bid -= 128;
    if (bid < 128) { long i = ((long)bid * 256 + threadIdx.x) * 8; pack_store8(W2 + i, w2_bf + i); return; }
    bid -= 128;
    if (bid < 512) { long i = ((long)bid * 256 + threadIdx.x) * 8; pack_store8(qpos + i, qpos_bf + i); return; }
    bid -= 512;
    if (bid < 4096) { long i = ((long)bid * 256 + threadIdx.x) * 8; pack_store8(vpos + i, vpos_bf + i); return; }
    bid -= 4096;
    {   // init: cur = query f32 + bf16
        long i = ((long)bid * 256 + threadIdx.x) * 8;
        float4 a = *(const float4*)&query[i];
        float4 b = *(const float4*)&query[i + 4];
        *(float4*)&cur[i] = a;
        *(float4*)&cur[i + 4] = b;
        uint4 v;
        v.x = pack2(a.x, a.y); v.y = pack2(a.z, a.w);
        v.z = pack2(b.x, b.y); v.w = pack2(b.z, b.w);
        *(uint4*)&cur_bf[i] = v;
    }
}

// ================ GEMM (W1/relu): out_bf = relu(A_bf@W_bf^T + bias) ================
__global__ __launch_bounds__(256) void gemm_k(
        const unsigned short* __restrict__ A, const unsigned short* __restrict__ W,
        const float* __restrict__ bias, unsigned short* __restrict__ out_bf) {
    __shared__ unsigned short sA[32 * 264];
    __shared__ unsigned short sB[64 * 264];
    const int t = threadIdx.x;
    const int lane = t & 63, wave = t >> 6, quad = lane >> 4, lid = lane & 15;
    const int row0 = blockIdx.x * 32, col0 = blockIdx.y * 64;
    {
        int r = t >> 3, ks = (t & 7) * 32;
        const unsigned short* ap = A + (long)(row0 + r) * E + ks;
#pragma unroll
        for (int i = 0; i < 4; i++)
            *(uint4*)&sA[r * 264 + ks + i * 8] = *(const uint4*)(ap + i * 8);
    }
    {
        int r = t >> 2, ks = (t & 3) * 64;
        const unsigned short* wp = W + (long)(col0 + r) * E + ks;
#pragma unroll
        for (int i = 0; i < 8; i++)
            *(uint4*)&sB[r * 264 + ks + i * 8] = *(const uint4*)(wp + i * 8);
    }
    __syncthreads();
    float4v acc[2];
    acc[0] = (float4v){0.f, 0.f, 0.f, 0.f};
    acc[1] = (float4v){0.f, 0.f, 0.f, 0.f};
#pragma unroll
    for (int k0 = 0; k0 < E; k0 += 32) {
        short8 bf = *(const short8*)&sB[(wave * 16 + lid) * 264 + k0 + quad * 8];
        short8 af0 = *(const short8*)&sA[(lid) * 264 + k0 + quad * 8];
        short8 af1 = *(const short8*)&sA[(16 + lid) * 264 + k0 + quad * 8];
        acc[0] = mfma16(af0, bf, acc[0]);
        acc[1] = mfma16(af1, bf, acc[1]);
    }
#pragma unroll
    for (int mt = 0; mt < 2; mt++)
#pragma unroll
        for (int r = 0; r < 4; r++) {
            int grow = row0 + mt * 16 + quad * 4 + r;
            int gcol = col0 + wave * 16 + lid;
            float v = fmaxf(acc[mt][r] + bias[gcol], 0.f);
            out_bf[(long)grow * E + gcol] = f2bf(v);
        }
}

// ================ fused GEMM + bias + residual + LayerNorm ================
template <int COMBINE, int OUT2>
__global__ __launch_bounds__(256, 1) void gemm_ln(
        const unsigned short* __restrict__ A,
        const float* __restrict__ Opart, const float* __restrict__ lp,
        const unsigned short* __restrict__ W, const float* __restrict__ bias,
        const float* __restrict__ res, const float* __restrict__ g,
        const float* __restrict__ bvec, float* __restrict__ outf,
        unsigned short* __restrict__ out_bf, float* __restrict__ outf2) {
    __shared__ unsigned short sA[16 * 264];
    __shared__ float lnS[4][16];
    __shared__ float lnQ[4][16];
    const int t = threadIdx.x;
    const int lane = t & 63, wave = t >> 6, quad = lane >> 4, lid = lane & 15;
    const int row0 = blockIdx.x * 16;
    {   // stage A tile: 16 rows x 256 cols bf16
        const int r = t >> 4, cseg = t & 15;
        if (COMBINE) {
            const int grow = row0 + r;
            const int seq = grow >> 2, b = grow & 3;
            const int h = cseg >> 1, dd = (cseg & 1) * 16;
            const int bh = b * 8 + h;
            float L = 0.f;
            float av[16];
#pragma unroll
            for (int j = 0; j < 16; j++) av[j] = 0.f;
#pragma unroll
            for (int s = 0; s < SPLITS; s++) {
                long rbase = (long)(s * 32 + bh) * 512 + seq;
                L += lp[rbase];
#pragma unroll
                for (int jj = 0; jj < 4; jj++) {
                    float4 p = *(const float4*)&Opart[rbase * 32 + dd + jj * 4];
                    av[jj * 4 + 0] += p.x; av[jj * 4 + 1] += p.y;
                    av[jj * 4 + 2] += p.z; av[jj * 4 + 3] += p.w;
                }
            }
            float inv = 1.f / L;
            uint4 u0, u1;
            u0.x = pack2(av[0] * inv, av[1] * inv);   u0.y = pack2(av[2] * inv, av[3] * inv);
            u0.z = pack2(av[4] * inv, av[5] * inv);   u0.w = pack2(av[6] * inv, av[7] * inv);
            u1.x = pack2(av[8] * inv, av[9] * inv);   u1.y = pack2(av[10] * inv, av[11] * inv);
            u1.z = pack2(av[12] * inv, av[13] * inv); u1.w = pack2(av[14] * inv, av[15] * inv);
            *(uint4*)&sA[r * 264 + cseg * 16] = u0;
            *(uint4*)&sA[r * 264 + cseg * 16 + 8] = u1;
        } else {
            const unsigned short* ap = A + (long)(row0 + r) * E + cseg * 16;
            *(uint4*)&sA[r * 264 + cseg * 16] = *(const uint4*)ap;
            *(uint4*)&sA[r * 264 + cseg * 16 + 8] = *(const uint4*)(ap + 8);
        }
    }
    __syncthreads();
    float4v acc[4];
#pragma unroll
    for (int nf = 0; nf < 4; nf++) acc[nf] = (float4v){0.f, 0.f, 0.f, 0.f};
#pragma unroll
    for (int k0 = 0; k0 < E; k0 += 32) {
        short8 af = *(const short8*)&sA[lid * 264 + k0 + quad * 8];
#pragma unroll
        for (int nf = 0; nf < 4; nf++) {
            short8 bf = *(const short8*)(W + (long)(wave * 64 + nf * 16 + lid) * E + k0 + quad * 8);
            acc[nf] = mfma16(af, bf, acc[nf]);
        }
    }
    float v[4][4];
    float sr[4], qr_[4];
#pragma unroll
    for (int r = 0; r < 4; r++) { sr[r] = 0.f; qr_[r] = 0.f; }
#pragma unroll
    for (int nf = 0; nf < 4; nf++) {
        int col = wave * 64 + nf * 16 + lid;
        float bcol = bias[col];
#pragma unroll
        for (int r = 0; r < 4; r++) {
            int grow = row0 + quad * 4 + r;
            float val = acc[nf][r] + bcol + res[(long)grow * E + col];
            v[nf][r] = val;
            sr[r] += val;
            qr_[r] += val * val;
        }
    }
#pragma unroll
    for (int r = 0; r < 4; r++) {
#pragma unroll
        for (int d = 1; d < 16; d <<= 1) {
            sr[r] += __shfl_xor(sr[r], d);
            qr_[r] += __shfl_xor(qr_[r], d);
        }
    }
    if (lid == 0) {
#pragma unroll
        for (int r = 0; r < 4; r++) {
            lnS[wave][quad * 4 + r] = sr[r];
            lnQ[wave][quad * 4 + r] = qr_[r];
        }
    }
    __syncthreads();
    float mean[4], rstd[4];
#pragma unroll
    for (int r = 0; r < 4; r++) {
        int row = quad * 4 + r;
        float S = lnS[0][row] + lnS[1][row] + lnS[2][row] + lnS[3][row];
        float Q = lnQ[0][row] + lnQ[1][row] + lnQ[2][row] + lnQ[3][row];
        float mu = S * (1.f / 256.f);
        mean[r] = mu;
        rstd[r] = rsqrtf(Q * (1.f / 256.f) - mu * mu + 1e-5f);
    }
#pragma unroll
    for (int nf = 0; nf < 4; nf++) {
        int col = wave * 64 + nf * 16 + lid;
        float gc = g[col], bc = bvec[col];
#pragma unroll
        for (int r = 0; r < 4; r++) {
            int grow = row0 + quad * 4 + r;
            float xo = (v[nf][r] - mean[r]) * rstd[r] * gc + bc;
            outf[(long)grow * E + col] = xo;
            out_bf[(long)grow * E + col] = f2bf(xo);
            if (OUT2) outf2[(long)grow * E + col] = xo;
        }
    }
}

// ================ Q projection + scale + rotary -> qbuf[b][h][lq][hd] bf16 ================
__global__ __launch_bounds__(256) void qkv_q(
        const unsigned short* __restrict__ A, const unsigned short* __restrict__ W,
        const float* __restrict__ bias, const unsigned short* __restrict__ pos,
        unsigned short* __restrict__ qout) {
    __shared__ unsigned short sA[32 * 40];
    __shared__ unsigned short sB[64 * 40];
    const int t = threadIdx.x;
    const int lane = t & 63, wave = t >> 6, quad = lane >> 4, lid = lane & 15;
    const int row0 = blockIdx.x * 32, col0 = blockIdx.y * 64;
    const int sr = t >> 2, sk = (t & 3) * 8;
    const unsigned short* ap = A + (long)(row0 + sr) * E + sk;
    const unsigned short* wp = W + (long)(col0 + sr) * E + sk;
    uint4 av, bv;
    if (t < 128) av = *(const uint4*)ap;
    bv = *(const uint4*)wp;
    float4v acc[2];
    acc[0] = (float4v){0.f, 0.f, 0.f, 0.f};
    acc[1] = (float4v){0.f, 0.f, 0.f, 0.f};
#pragma unroll
    for (int ki = 0; ki < 8; ki++) {
        __syncthreads();
        if (t < 128) *(uint4*)&sA[sr * 40 + sk] = av;
        *(uint4*)&sB[sr * 40 + sk] = bv;
        __syncthreads();
        if (ki < 7) {
            if (t < 128) av = *(const uint4*)(ap + (ki + 1) * 32);
            bv = *(const uint4*)(wp + (ki + 1) * 32);
        }
        short8 af0 = *(const short8*)&sA[lid * 40 + quad * 8];
        short8 af1 = *(const short8*)&sA[(16 + lid) * 40 + quad * 8];
        short8 bf = *(const short8*)&sB[(wave * 16 + lid) * 40 + quad * 8];
        acc[0] = mfma16(af0, bf, acc[0]);
        acc[1] = mfma16(af1, bf, acc[1]);
    }
#pragma unroll
    for (int mt = 0; mt < 2; mt++)
#pragma unroll
        for (int r = 0; r < 4; r++) {
            int grow = row0 + mt * 16 + quad * 4 + r;
            int gcol = col0 + wave * 16 + lid;
            float v = (acc[mt][r] + bias[gcol]) * QSCALE;
            int seq = grow >> 2, b = grow & 3;
            int c = gcol;
            unsigned int cs = *(const unsigned int*)&pos[(((long)b * LQ + seq) * E + c) * 2];
            float cv = bf2f((unsigned short)cs), sv = bf2f((unsigned short)(cs >> 16));
            float p = __shfl_xor(v, 1);
            float x2 = (c & 1) ? p : -p;
            float rv = v * cv + x2 * sv;
            qout[(((long)b * NH + (c >> 5)) * LQ + seq) * HD + (c & 31)] = f2bf(rv);
        }
}

// ================ KV projection v4: layer loop inside; A-tile staged ONCE; W from L2 ================
// grid (256 row-tiles, 8 col-tiles), 256 thr = 4 waves (2x2). Cuts L3-level A traffic 4x
// (redundancy 32x -> 8x) and vpos reads 4x (rotary cos/sin held in regs across layers).
__global__ __launch_bounds__(256) void qkv_kv(
        const unsigned short* __restrict__ A, const unsigned short* __restrict__ Wall,
        const float* __restrict__ ball, const unsigned short* __restrict__ pos,
        unsigned short* __restrict__ kall, unsigned short* __restrict__ vtall) {
    __shared__ unsigned short sA[64 * 264];   // 33.8 KB: full-K A tile, lives across layers
    __shared__ unsigned short sT[64 * 72];    // 9.2 KB: V transpose scratch
    const int t = threadIdx.x;
    const int lane = t & 63, wave = t >> 6, quad = lane >> 4, lid = lane & 15;
    const int wr = wave >> 1, wc = wave & 1;
    const int row0 = blockIdx.x * 64, col0 = blockIdx.y * 64;
    const int b = row0 >> 12, seq0 = row0 & 4095;
    const bool khalf_blk = (col0 < 256);   // block-uniform
    {   // stage A once: 64 rows x 256 K
        const int r = t >> 2, kk = (t & 3) * 64;
        const unsigned short* ap = A + (long)(row0 + r) * E + kk;
#pragma unroll
        for (int i = 0; i < 8; i++)
            *(uint4*)&sA[r * 264 + kk + i * 8] = *(const uint4*)(ap + i * 8);
    }
    // K-half: preload rotary cos/sin (layer-invariant) into 16 regs
    unsigned int cs[2][2][4];
    if (khalf_blk) {
#pragma unroll
        for (int mt = 0; mt < 2; mt++)
#pragma unroll
            for (int nt = 0; nt < 2; nt++)
#pragma unroll
                for (int rr = 0; rr < 4; rr++) {
                    int seq = seq0 + wr * 32 + mt * 16 + quad * 4 + rr;
                    int c = col0 + wc * 32 + nt * 16 + lid;
                    cs[mt][nt][rr] = *(const unsigned int*)&pos[(((long)b * LKV + seq) * E + c) * 2];
                }
    }
    __syncthreads();
    const unsigned short* wb0base = Wall + 256 * 256 + (long)(col0 + wc * 32 + lid) * E;
    const unsigned short* wb1base = Wall + 256 * 256 + (long)(col0 + wc * 32 + 16 + lid) * E;
    for (int layer = 0; layer < NLAYER; layer++) {
        const float* bias = ball + (long)layer * 768 + 256;
        const unsigned short* wb0 = wb0base + (long)layer * 768 * 256;
        const unsigned short* wb1 = wb1base + (long)layer * 768 * 256;
        float4v acc[2][2];
#pragma unroll
        for (int i = 0; i < 2; i++)
#pragma unroll
            for (int j = 0; j < 2; j++) acc[i][j] = (float4v){0.f, 0.f, 0.f, 0.f};
#pragma unroll
        for (int k0 = 0; k0 < E; k0 += 32) {
            short8 bf0 = *(const short8*)(wb0 + k0 + quad * 8);   // L2-hot W stream
            short8 bf1 = *(const short8*)(wb1 + k0 + quad * 8);
            short8 af0 = *(const short8*)&sA[(wr * 32 + lid) * 264 + k0 + quad * 8];
            short8 af1 = *(const short8*)&sA[(wr * 32 + 16 + lid) * 264 + k0 + quad * 8];
            acc[0][0] = mfma16(af0, bf0, acc[0][0]);
            acc[0][1] = mfma16(af0, bf1, acc[0][1]);
            acc[1][0] = mfma16(af1, bf0, acc[1][0]);
            acc[1][1] = mfma16(af1, bf1, acc[1][1]);
        }
        if (khalf_blk) {  // ---- K: rotary from regs, direct stores ----
            unsigned short* kout = kall + (long)layer * 4194304;
#pragma unroll
            for (int mt = 0; mt < 2; mt++)
#pragma unroll
                for (int nt = 0; nt < 2; nt++)
#pragma unroll
                    for (int rr = 0; rr < 4; rr++) {
                        int c = col0 + wc * 32 + nt * 16 + lid;
                        int seq = seq0 + wr * 32 + mt * 16 + quad * 4 + rr;
                        float v = acc[mt][nt][rr] + bias[c];
                        unsigned int u = cs[mt][nt][rr];
                        float cv = bf2f((unsigned short)u), sv = bf2f((unsigned short)(u >> 16));
                        float p = __shfl_xor(v, 1);
                        float x2 = (c & 1) ? p : -p;
                        float rv = v * cv + x2 * sv;
                        kout[(((long)b * NH + (c >> 5)) * LKV + seq) * HD + (c & 31)] = f2bf(rv);
                    }
        } else {          // ---- V: LDS transpose then coalesced writes ----
            unsigned short* vtout = vtall + (long)layer * 4194304;
            __syncthreads();   // prior layer's sT reads complete (block-uniform branch)
#pragma unroll
            for (int mt = 0; mt < 2; mt++)
#pragma unroll
                for (int nt = 0; nt < 2; nt++) {
                    int cl = wc * 32 + nt * 16 + lid;
                    int so = wr * 32 + mt * 16 + quad * 4;
                    float bcol = bias[col0 + cl];
                    uint2 pw;
                    pw.x = pack2(acc[mt][nt][0] + bcol, acc[mt][nt][1] + bcol);
                    pw.y = pack2(acc[mt][nt][2] + bcol, acc[mt][nt][3] + bcol);
                    *(uint2*)&sT[cl * 72 + so] = pw;
                }
            __syncthreads();
            const int cl = t >> 2, sc = (t & 3) * 16;
            uint4 u0 = *(const uint4*)&sT[cl * 72 + sc];
            uint4 u1 = *(const uint4*)&sT[cl * 72 + sc + 8];
            int cg = (col0 - 256) + cl;
            unsigned short* dst = vtout + (((long)b * NH + (cg >> 5)) * HD + (cg & 31)) * (long)LKV + seq0 + sc;
            *(uint4*)dst = u0;
            *(uint4*)(dst + 8) = u1;
        }
    }
}

// ================ flash attention, split-KV(8), no online max, fenced sPT reuse (R7-proven) ================
__global__ __launch_bounds__(256) void attn_k(
        const unsigned short* __restrict__ qb, const unsigned short* __restrict__ kb,
        const unsigned short* __restrict__ vtb, float* __restrict__ Opart,
        float* __restrict__ lpart) {
    __shared__ unsigned short sK[CK * 40];       // 10.0 KB
    __shared__ unsigned short sVT[32 * 136];     // 8.5 KB
    __shared__ unsigned short sPT[4 * 64 * 36];  // 18.0 KB (per-wave, 64-key sub-chunk)
    const int t = threadIdx.x;
    const int lane = t & 63, wave = t >> 6, quad = lane >> 4, lid = lane & 15;
    const int qt0 = blockIdx.x * QT;
    const int bh = blockIdx.y;
    const int key0 = blockIdx.z * KSPAN;
    const unsigned short* kbase = kb + (long)bh * LKV * HD;
    const unsigned short* vbase = vtb + (long)bh * HD * LKV;
    short8 aq[2];
#pragma unroll
    for (int mf = 0; mf < 2; mf++)
        aq[mf] = *(const short8*)(qb + ((long)bh * LQ + qt0 + wave * 32 + mf * 16 + lid) * HD + quad * 8);
    float4v o[2][2];
#pragma unroll
    for (int i = 0; i < 2; i++) for (int j = 0; j < 2; j++) o[i][j] = (float4v){0.f, 0.f, 0.f, 0.f};
    float l[8] = {0.f, 0.f, 0.f, 0.f, 0.f, 0.f, 0.f, 0.f};
    const int krow = t >> 1, khalf = (t & 1) * 16;
    const int vrow = t >> 3, vkoff = (t & 7) * 16;
    unsigned short* myPT = &sPT[wave * 64 * 36];
    uint4 kv0 = *(const uint4*)(kbase + (long)(key0 + krow) * HD + khalf);
    uint4 kv1 = *(const uint4*)(kbase + (long)(key0 + krow) * HD + khalf + 8);
    uint4 vv0 = *(const uint4*)(vbase + (long)vrow * LKV + key0 + vkoff);
    uint4 vv1 = *(const uint4*)(vbase + (long)vrow * LKV + key0 + vkoff + 8);
    for (int ck = key0; ck < key0 + KSPAN; ck += CK) {
        __syncthreads();
        *(uint4*)&sK[krow * 40 + khalf] = kv0;
        *(uint4*)&sK[krow * 40 + khalf + 8] = kv1;
        *(uint4*)&sVT[vrow * 136 + vkoff] = vv0;
        *(uint4*)&sVT[vrow * 136 + vkoff + 8] = vv1;
        __syncthreads();
        if (ck + CK < key0 + KSPAN) {   // prefetch next chunk
            kv0 = *(const uint4*)(kbase + (long)(ck + CK + krow) * HD + khalf);
            kv1 = *(const uint4*)(kbase + (long)(ck + CK + krow) * HD + khalf + 8);
            vv0 = *(const uint4*)(vbase + (long)vrow * LKV + ck + CK + vkoff);
            vv1 = *(const uint4*)(vbase + (long)vrow * LKV + ck + CK + vkoff + 8);
        }
#pragma unroll
        for (int half = 0; half < 2; half++) {
#pragma unroll
            for (int nf = 0; nf < 4; nf++) {
                short8 bk = *(const short8*)&sK[(half * 64 + nf * 16 + lid) * 40 + quad * 8];
#pragma unroll
                for (int mf = 0; mf < 2; mf++) {
                    float4v z = (float4v){0.f, 0.f, 0.f, 0.f};
                    float4v s = mfma16(aq[mf], bk, z);
                    float e0 = __expf(s[0]), e1 = __expf(s[1]);
                    float e2 = __expf(s[2]), e3 = __expf(s[3]);
                    l[mf * 4 + 0] += e0; l[mf * 4 + 1] += e1;
                    l[mf * 4 + 2] += e2; l[mf * 4 + 3] += e3;
                    uint2 pk;
                    pk.x = pack2_rtz(e0, e1);
                    pk.y = pack2_rtz(e2, e3);
                    *(uint2*)&myPT[(nf * 16 + lid) * 36 + mf * 16 + quad * 4] = pk;
                }
            }
            LDS_FENCE();   // P writes drained before cross-lane reads (no barrier here!)
#pragma unroll
            for (int kb2 = 0; kb2 < 2; kb2++) {
                short8 bv0 = *(const short8*)&sVT[lid * 136 + half * 64 + kb2 * 32 + quad * 8];
                short8 bv1 = *(const short8*)&sVT[(16 + lid) * 136 + half * 64 + kb2 * 32 + quad * 8];
#pragma unroll
                for (int mf = 0; mf < 2; mf++) {
                    short8 ap;
#pragma unroll
                    for (int j = 0; j < 8; j++)
                        ap[j] = (short)myPT[(kb2 * 32 + quad * 8 + j) * 36 + mf * 16 + lid];
                    o[mf][0] = mfma16(ap, bv0, o[mf][0]);
                    o[mf][1] = mfma16(ap, bv1, o[mf][1]);
                }
            }
            LDS_FENCE();   // P reads drained before next half overwrites myPT
        }
    }
#pragma unroll
    for (int i = 0; i < 8; i++) {
#pragma unroll
        for (int d = 1; d < 16; d <<= 1) l[i] += __shfl_xor(l[i], d);
    }
#pragma unroll
    for (int mf = 0; mf < 2; mf++)
#pragma unroll
        for (int r = 0; r < 4; r++) {
            long orow = ((long)blockIdx.z * 32 + bh) * LQ + qt0 + wave * 32 + mf * 16 + quad * 4 + r;
            Opart[orow * HD + lid] = o[mf][0][r];
            Opart[orow * HD + 16 + lid] = o[mf][1][r];
            if (lid == 0) lpart[orow] = l[mf * 4 + r];
        }
}

extern "C" void kernel_launch(void* const* d_in, const int* in_sizes, int n_in,
                              void* d_out, int out_size, void* d_ws, size_t ws_size,
                              hipStream_t stream) {
    (void)in_sizes; (void)n_in; (void)out_size; (void)ws_size;
    const float* query = (const float*)d_in[0];
    const float* value = (const float*)d_in[1];
    const float* qpos  = (const float*)d_in[2];
    const float* vpos  = (const float*)d_in[3];
    const float* Wqkv  = (const float*)d_in[4];
    const float* bqkv  = (const float*)d_in[5];
    const float* Wo    = (const float*)d_in[6];
    const float* bo    = (const float*)d_in[7];
    const float* g1    = (const float*)d_in[8];
    const float* be1   = (const float*)d_in[9];
    const float* W1    = (const float*)d_in[10];
    const float* b1    = (const float*)d_in[11];
    const float* W2    = (const float*)d_in[12];
    const float* b2    = (const float*)d_in[13];
    const float* g2    = (const float*)d_in[14];
    const float* be2   = (const float*)d_in[15];
    float* outp = (float*)d_out;

    char* w = (char*)d_ws;
    float*          cur     = (float*)(w + 0);                     // 2 MB
    unsigned short* cur_bf  = (unsigned short*)(w + (2l  << 20));  // 1 MB
    unsigned short* qbuf    = (unsigned short*)(w + (3l  << 20));  // 1 MB
    float*          xb      = (float*)(w + (4l  << 20));           // 2 MB
    unsigned short* xb_bf   = (unsigned short*)(w + (6l  << 20));  // 1 MB
    unsigned short* h1b_bf  = (unsigned short*)(w + (7l  << 20));  // 1 MB
    float*          lp      = (float*)(w + (8l  << 20));           // 512 KB
    float*          Opart   = (float*)(w + (9l  << 20));           // 16 MB
    unsigned short* val_t   = (unsigned short*)(w + (25l << 20));  // 8 MB  [b][seq][E]
    unsigned short* wqkv_bf = (unsigned short*)(w + (33l << 20));  // 1.5 MB
    unsigned short* wo_bf   = (unsigned short*)(w + (35l << 20));  // 0.5 MB
    unsigned short* w1_bf   = (unsigned short*)(w + (36l << 20));  // 0.5 MB
    unsigned short* w2_bf   = (unsigned short*)(w + (37l << 20));  // 0.5 MB
    unsigned short* qpos_bf = (unsigned short*)(w + (38l << 20));  // 2 MB
    unsigned short* vpos_bf = (unsigned short*)(w + (40l << 20));  // 16 MB
    unsigned short* kbuf    = (unsigned short*)(w + (56l << 20));  // 32 MB (4 layers)
    unsigned short* vtb     = (unsigned short*)(w + (88l << 20));  // 32 MB (4 layers)

    pack_all<<<7680, 256, 0, stream>>>(value, Wqkv, Wo, W1, W2, qpos, vpos, query,
                                       val_t, wqkv_bf, wo_bf, w1_bf, w2_bf, qpos_bf,
                                       vpos_bf, cur, cur_bf);

    // all 4 layers' KV projection in one launch; layer loop inside (A staged once per block)
    qkv_kv<<<dim3(256, 8), 256, 0, stream>>>(val_t, wqkv_bf, bqkv, vpos_bf, kbuf, vtb);

    for (int layer = 0; layer < NLAYER; layer++) {
        const unsigned short* Wl = wqkv_bf + (long)layer * 768 * 256;
        const float* bl = bqkv + (long)layer * 768;
        qkv_q<<<dim3(64, 4), 256, 0, stream>>>(cur_bf, Wl, bl, qpos_bf, qbuf);
        attn_k<<<dim3(LQ / QT, 32, SPLITS), 256, 0, stream>>>(
            qbuf, kbuf + (long)layer * 4194304, vtb + (long)layer * 4194304, Opart, lp);
        gemm_ln<1, 0><<<128, 256, 0, stream>>>(
            nullptr, Opart, lp, wo_bf + layer * 65536, bo + layer * 256,
            cur, g1 + layer * 256, be1 + layer * 256, xb, xb_bf, nullptr);
        gemm_k<<<dim3(64, 4), 256, 0, stream>>>(xb_bf, w1_bf + layer * 65536, b1 + layer * 256, h1b_bf);
        gemm_ln<0, 1><<<128, 256, 0, stream>>>(
            h1b_bf, nullptr, nullptr, w2_bf + layer * 65536, b2 + layer * 256,
            xb, g2 + layer * 256, be2 + layer * 256, cur, cur_bf,
            outp + (long)layer * LQ * NB * E);
    }
}

// Round 10
// 359.425 us; speedup vs baseline: 1.1754x; 1.1754x over previous
//
#include <hip/hip_runtime.h>
#include <hip/hip_bf16.h>

typedef __attribute__((ext_vector_type(8))) short short8;
typedef __attribute__((ext_vector_type(4))) float float4v;

#define LQ 512
#define NB 4
#define LKV 4096
#define E 256
#define NH 8
#define HD 32
#define NLAYER 4
#define QSCALE 0.17677669529663687f
#define SPLITS 8
#define KSPAN (LKV / SPLITS)
#define QT 128   // q rows per attn block
#define CK 128   // keys per attn chunk

// drain wave's LDS queue + forbid compiler reordering of LDS ops across this point.
// REQUIRED around wave-private cross-lane LDS reuse (myPT). [R6 post-timing race]
#define LDS_FENCE() asm volatile("s_waitcnt lgkmcnt(0)" ::: "memory")

__device__ __forceinline__ unsigned short f2bf(float f) {
    union { float f; unsigned int i; } x; x.f = f;
    unsigned int r = x.i + 0x7fffu + ((x.i >> 16) & 1u);
    return (unsigned short)(r >> 16);
}
__device__ __forceinline__ unsigned int pack2(float a, float b) {
    union { float f; unsigned int i; } xa, xb; xa.f = a; xb.f = b;
    unsigned int ra = xa.i + 0x7fffu + ((xa.i >> 16) & 1u);
    unsigned int rb = xb.i + 0x7fffu + ((xb.i >> 16) & 1u);
    return (ra >> 16) | (rb & 0xffff0000u);
}
__device__ __forceinline__ unsigned int pack2_rtz(float a, float b) {
    union { float f; unsigned int i; } xa, xb; xa.f = a; xb.f = b;
    return __builtin_amdgcn_perm(xb.i, xa.i, 0x07060302u);
}
__device__ __forceinline__ float bf2f(unsigned short u) {
    union { unsigned int i; float f; } x; x.i = ((unsigned int)u) << 16; return x.f;
}
__device__ __forceinline__ float4v mfma16(short8 a, short8 b, float4v c) {
    return __builtin_amdgcn_mfma_f32_16x16x32_bf16(a, b, c, 0, 0, 0);
}
__device__ __forceinline__ void pack_store8(const float* __restrict__ src,
                                            unsigned short* __restrict__ dst) {
    float4 a = *(const float4*)src;
    float4 b = *(const float4*)(src + 4);
    uint4 v;
    v.x = pack2(a.x, a.y); v.y = pack2(a.z, a.w);
    v.z = pack2(b.x, b.y); v.w = pack2(b.z, b.w);
    *(uint4*)dst = v;
}

// ================ one mega pre-pass: all packs + val b-major transpose + init ================
__global__ void pack_all(const float* __restrict__ value, const float* __restrict__ Wqkv,
                         const float* __restrict__ Wo, const float* __restrict__ W1,
                         const float* __restrict__ W2, const float* __restrict__ qpos,
                         const float* __restrict__ vpos, const float* __restrict__ query,
                         unsigned short* __restrict__ val_t, unsigned short* __restrict__ wqkv_bf,
                         unsigned short* __restrict__ wo_bf, unsigned short* __restrict__ w1_bf,
                         unsigned short* __restrict__ w2_bf, unsigned short* __restrict__ qpos_bf,
                         unsigned short* __restrict__ vpos_bf, float* __restrict__ cur,
                         unsigned short* __restrict__ cur_bf) {
    int bid = blockIdx.x;
    if (bid < 2048) {  // value -> val_t [b][seq][E] bf16
        long idx = ((long)bid * 256 + threadIdx.x) * 8;
        int ro = (int)(idx >> 8), e = (int)(idx & 255);
        int ri = ((ro & 4095) << 2) | (ro >> 12);   // in-row = seq*4 + b
        pack_store8(value + (long)ri * 256 + e, val_t + idx);
        return;
    }
    bid -= 2048;
    if (bid < 384) { long i = ((long)bid * 256 + threadIdx.x) * 8; pack_store8(Wqkv + i, wqkv_bf + i); return; }
    bid -= 384;
    if (bid < 128) { long i = ((long)bid * 256 + threadIdx.x) * 8; pack_store8(Wo + i, wo_bf + i); return; }
    bid -= 128;
    if (bid < 128) { long i = ((long)bid * 256 + threadIdx.x) * 8; pack_store8(W1 + i, w1_bf + i); return; }
    bid -= 128;
    if (bid < 128) { long i = ((long)bid * 256 + threadIdx.x) * 8; pack_store8(W2 + i, w2_bf + i); return; }
    bid -= 128;
    if (bid < 512) { long i = ((long)bid * 256 + threadIdx.x) * 8; pack_store8(qpos + i, qpos_bf + i); return; }
    bid -= 512;
    if (bid < 4096) { long i = ((long)bid * 256 + threadIdx.x) * 8; pack_store8(vpos + i, vpos_bf + i); return; }
    bid -= 4096;
    {   // init: cur = query f32 + bf16
        long i = ((long)bid * 256 + threadIdx.x) * 8;
        float4 a = *(const float4*)&query[i];
        float4 b = *(const float4*)&query[i + 4];
        *(float4*)&cur[i] = a;
        *(float4*)&cur[i + 4] = b;
        uint4 v;
        v.x = pack2(a.x, a.y); v.y = pack2(a.z, a.w);
        v.z = pack2(b.x, b.y); v.w = pack2(b.z, b.w);
        *(uint4*)&cur_bf[i] = v;
    }
}

// ================ GEMM (W1/relu): out_bf = relu(A_bf@W_bf^T + bias) ================
__global__ __launch_bounds__(256) void gemm_k(
        const unsigned short* __restrict__ A, const unsigned short* __restrict__ W,
        const float* __restrict__ bias, unsigned short* __restrict__ out_bf) {
    __shared__ unsigned short sA[32 * 264];
    __shared__ unsigned short sB[64 * 264];
    const int t = threadIdx.x;
    const int lane = t & 63, wave = t >> 6, quad = lane >> 4, lid = lane & 15;
    const int row0 = blockIdx.x * 32, col0 = blockIdx.y * 64;
    {
        int r = t >> 3, ks = (t & 7) * 32;
        const unsigned short* ap = A + (long)(row0 + r) * E + ks;
#pragma unroll
        for (int i = 0; i < 4; i++)
            *(uint4*)&sA[r * 264 + ks + i * 8] = *(const uint4*)(ap + i * 8);
    }
    {
        int r = t >> 2, ks = (t & 3) * 64;
        const unsigned short* wp = W + (long)(col0 + r) * E + ks;
#pragma unroll
        for (int i = 0; i < 8; i++)
            *(uint4*)&sB[r * 264 + ks + i * 8] = *(const uint4*)(wp + i * 8);
    }
    __syncthreads();
    float4v acc[2];
    acc[0] = (float4v){0.f, 0.f, 0.f, 0.f};
    acc[1] = (float4v){0.f, 0.f, 0.f, 0.f};
#pragma unroll
    for (int k0 = 0; k0 < E; k0 += 32) {
        short8 bf = *(const short8*)&sB[(wave * 16 + lid) * 264 + k0 + quad * 8];
        short8 af0 = *(const short8*)&sA[(lid) * 264 + k0 + quad * 8];
        short8 af1 = *(const short8*)&sA[(16 + lid) * 264 + k0 + quad * 8];
        acc[0] = mfma16(af0, bf, acc[0]);
        acc[1] = mfma16(af1, bf, acc[1]);
    }
#pragma unroll
    for (int mt = 0; mt < 2; mt++)
#pragma unroll
        for (int r = 0; r < 4; r++) {
            int grow = row0 + mt * 16 + quad * 4 + r;
            int gcol = col0 + wave * 16 + lid;
            float v = fmaxf(acc[mt][r] + bias[gcol], 0.f);
            out_bf[(long)grow * E + gcol] = f2bf(v);
        }
}

// ================ fused GEMM + bias + residual + LayerNorm (W preloaded to registers) ================
// COMBINE=1: A built from bf16 split-KV partials (Opart/lp). OUT2: extra f32 copy (layer out).
template <int COMBINE, int OUT2>
__global__ __launch_bounds__(256, 1) void gemm_ln(
        const unsigned short* __restrict__ A,
        const unsigned short* __restrict__ Opart, const float* __restrict__ lp,
        const unsigned short* __restrict__ W, const float* __restrict__ bias,
        const float* __restrict__ res, const float* __restrict__ g,
        const float* __restrict__ bvec, float* __restrict__ outf,
        unsigned short* __restrict__ out_bf, float* __restrict__ outf2) {
    __shared__ unsigned short sA[16 * 264];
    __shared__ float lnS[4][16];
    __shared__ float lnQ[4][16];
    const int t = threadIdx.x;
    const int lane = t & 63, wave = t >> 6, quad = lane >> 4, lid = lane & 15;
    const int row0 = blockIdx.x * 16;
    // W into registers: 32 independent b128 loads issue up-front (no sA dependency)
    short8 wreg[8][4];
#pragma unroll
    for (int k0 = 0; k0 < 8; k0++)
#pragma unroll
        for (int nf = 0; nf < 4; nf++)
            wreg[k0][nf] = *(const short8*)(W + (long)(wave * 64 + nf * 16 + lid) * E + k0 * 32 + quad * 8);
    {   // stage A tile: 16 rows x 256 cols bf16
        const int r = t >> 4, cseg = t & 15;
        if (COMBINE) {
            const int grow = row0 + r;
            const int seq = grow >> 2, b = grow & 3;
            const int h = cseg >> 1, dd = (cseg & 1) * 16;
            const int bh = b * 8 + h;
            float L = 0.f;
            float av[16];
#pragma unroll
            for (int j = 0; j < 16; j++) av[j] = 0.f;
#pragma unroll
            for (int s = 0; s < SPLITS; s++) {
                long rbase = (long)(s * 32 + bh) * 512 + seq;
                L += lp[rbase];
                const unsigned short* op = Opart + rbase * 32 + dd;
                uint4 u0 = *(const uint4*)op;
                uint4 u1 = *(const uint4*)(op + 8);
                av[0]  += bf2f((unsigned short)u0.x); av[1]  += bf2f((unsigned short)(u0.x >> 16));
                av[2]  += bf2f((unsigned short)u0.y); av[3]  += bf2f((unsigned short)(u0.y >> 16));
                av[4]  += bf2f((unsigned short)u0.z); av[5]  += bf2f((unsigned short)(u0.z >> 16));
                av[6]  += bf2f((unsigned short)u0.w); av[7]  += bf2f((unsigned short)(u0.w >> 16));
                av[8]  += bf2f((unsigned short)u1.x); av[9]  += bf2f((unsigned short)(u1.x >> 16));
                av[10] += bf2f((unsigned short)u1.y); av[11] += bf2f((unsigned short)(u1.y >> 16));
                av[12] += bf2f((unsigned short)u1.z); av[13] += bf2f((unsigned short)(u1.z >> 16));
                av[14] += bf2f((unsigned short)u1.w); av[15] += bf2f((unsigned short)(u1.w >> 16));
            }
            float inv = 1.f / L;
            uint4 u0, u1;
            u0.x = pack2(av[0] * inv, av[1] * inv);   u0.y = pack2(av[2] * inv, av[3] * inv);
            u0.z = pack2(av[4] * inv, av[5] * inv);   u0.w = pack2(av[6] * inv, av[7] * inv);
            u1.x = pack2(av[8] * inv, av[9] * inv);   u1.y = pack2(av[10] * inv, av[11] * inv);
            u1.z = pack2(av[12] * inv, av[13] * inv); u1.w = pack2(av[14] * inv, av[15] * inv);
            *(uint4*)&sA[r * 264 + cseg * 16] = u0;
            *(uint4*)&sA[r * 264 + cseg * 16 + 8] = u1;
        } else {
            const unsigned short* ap = A + (long)(row0 + r) * E + cseg * 16;
            *(uint4*)&sA[r * 264 + cseg * 16] = *(const uint4*)ap;
            *(uint4*)&sA[r * 264 + cseg * 16 + 8] = *(const uint4*)(ap + 8);
        }
    }
    __syncthreads();
    short8 ar[8];
#pragma unroll
    for (int k0 = 0; k0 < 8; k0++)
        ar[k0] = *(const short8*)&sA[lid * 264 + k0 * 32 + quad * 8];
    float4v acc[4];
#pragma unroll
    for (int nf = 0; nf < 4; nf++) acc[nf] = (float4v){0.f, 0.f, 0.f, 0.f};
#pragma unroll
    for (int k0 = 0; k0 < 8; k0++)
#pragma unroll
        for (int nf = 0; nf < 4; nf++)
            acc[nf] = mfma16(ar[k0], wreg[k0][nf], acc[nf]);
    float v[4][4];
    float sr[4], qr_[4];
#pragma unroll
    for (int r = 0; r < 4; r++) { sr[r] = 0.f; qr_[r] = 0.f; }
#pragma unroll
    for (int nf = 0; nf < 4; nf++) {
        int col = wave * 64 + nf * 16 + lid;
        float bcol = bias[col];
#pragma unroll
        for (int r = 0; r < 4; r++) {
            int grow = row0 + quad * 4 + r;
            float val = acc[nf][r] + bcol + res[(long)grow * E + col];
            v[nf][r] = val;
            sr[r] += val;
            qr_[r] += val * val;
        }
    }
#pragma unroll
    for (int r = 0; r < 4; r++) {
#pragma unroll
        for (int d = 1; d < 16; d <<= 1) {
            sr[r] += __shfl_xor(sr[r], d);
            qr_[r] += __shfl_xor(qr_[r], d);
        }
    }
    if (lid == 0) {
#pragma unroll
        for (int r = 0; r < 4; r++) {
            lnS[wave][quad * 4 + r] = sr[r];
            lnQ[wave][quad * 4 + r] = qr_[r];
        }
    }
    __syncthreads();
    float mean[4], rstd[4];
#pragma unroll
    for (int r = 0; r < 4; r++) {
        int row = quad * 4 + r;
        float S = lnS[0][row] + lnS[1][row] + lnS[2][row] + lnS[3][row];
        float Q = lnQ[0][row] + lnQ[1][row] + lnQ[2][row] + lnQ[3][row];
        float mu = S * (1.f / 256.f);
        mean[r] = mu;
        rstd[r] = rsqrtf(Q * (1.f / 256.f) - mu * mu + 1e-5f);
    }
#pragma unroll
    for (int nf = 0; nf < 4; nf++) {
        int col = wave * 64 + nf * 16 + lid;
        float gc = g[col], bc = bvec[col];
#pragma unroll
        for (int r = 0; r < 4; r++) {
            int grow = row0 + quad * 4 + r;
            float xo = (v[nf][r] - mean[r]) * rstd[r] * gc + bc;
            outf[(long)grow * E + col] = xo;
            out_bf[(long)grow * E + col] = f2bf(xo);
            if (OUT2) outf2[(long)grow * E + col] = xo;
        }
    }
}

// ================ Q projection + scale + rotary -> qbuf[b][h][lq][hd] bf16 ================
__global__ __launch_bounds__(256) void qkv_q(
        const unsigned short* __restrict__ A, const unsigned short* __restrict__ W,
        const float* __restrict__ bias, const unsigned short* __restrict__ pos,
        unsigned short* __restrict__ qout) {
    __shared__ unsigned short sA[32 * 40];
    __shared__ unsigned short sB[64 * 40];
    const int t = threadIdx.x;
    const int lane = t & 63, wave = t >> 6, quad = lane >> 4, lid = lane & 15;
    const int row0 = blockIdx.x * 32, col0 = blockIdx.y * 64;
    const int sr = t >> 2, sk = (t & 3) * 8;
    const unsigned short* ap = A + (long)(row0 + sr) * E + sk;
    const unsigned short* wp = W + (long)(col0 + sr) * E + sk;
    uint4 av, bv;
    if (t < 128) av = *(const uint4*)ap;
    bv = *(const uint4*)wp;
    float4v acc[2];
    acc[0] = (float4v){0.f, 0.f, 0.f, 0.f};
    acc[1] = (float4v){0.f, 0.f, 0.f, 0.f};
#pragma unroll
    for (int ki = 0; ki < 8; ki++) {
        __syncthreads();
        if (t < 128) *(uint4*)&sA[sr * 40 + sk] = av;
        *(uint4*)&sB[sr * 40 + sk] = bv;
        __syncthreads();
        if (ki < 7) {
            if (t < 128) av = *(const uint4*)(ap + (ki + 1) * 32);
            bv = *(const uint4*)(wp + (ki + 1) * 32);
        }
        short8 af0 = *(const short8*)&sA[lid * 40 + quad * 8];
        short8 af1 = *(const short8*)&sA[(16 + lid) * 40 + quad * 8];
        short8 bf = *(const short8*)&sB[(wave * 16 + lid) * 40 + quad * 8];
        acc[0] = mfma16(af0, bf, acc[0]);
        acc[1] = mfma16(af1, bf, acc[1]);
    }
#pragma unroll
    for (int mt = 0; mt < 2; mt++)
#pragma unroll
        for (int r = 0; r < 4; r++) {
            int grow = row0 + mt * 16 + quad * 4 + r;
            int gcol = col0 + wave * 16 + lid;
            float v = (acc[mt][r] + bias[gcol]) * QSCALE;
            int seq = grow >> 2, b = grow & 3;
            int c = gcol;
            unsigned int cs = *(const unsigned int*)&pos[(((long)b * LQ + seq) * E + c) * 2];
            float cv = bf2f((unsigned short)cs), sv = bf2f((unsigned short)(cs >> 16));
            float p = __shfl_xor(v, 1);
            float x2 = (c & 1) ? p : -p;
            float rv = v * cv + x2 * sv;
            qout[(((long)b * NH + (c >> 5)) * LQ + seq) * HD + (c & 31)] = f2bf(rv);
        }
}

// ================ KV projection (R8-proven v3): sT aliased onto sA, 18.4 KB LDS ================
__global__ __launch_bounds__(256) void qkv_kv(
        const unsigned short* __restrict__ A, const unsigned short* __restrict__ Wall,
        const float* __restrict__ ball, const unsigned short* __restrict__ pos,
        unsigned short* __restrict__ kall, unsigned short* __restrict__ vtall) {
    const int layer = blockIdx.z;
    const unsigned short* W = Wall + (long)layer * 768 * 256 + 256 * 256;
    const float* bias = ball + (long)layer * 768 + 256;
    unsigned short* kout = kall + (long)layer * 4194304;
    unsigned short* vtout = vtall + (long)layer * 4194304;
    __shared__ unsigned short smem[2 * 64 * 72];
    unsigned short* sA = smem;
    unsigned short* sB = smem + 64 * 72;
    const int t = threadIdx.x;
    const int lane = t & 63, wave = t >> 6, quad = lane >> 4, lid = lane & 15;
    const int wr = wave >> 1, wc = wave & 1;
    const int row0 = blockIdx.x * 64, col0 = blockIdx.y * 64;
    const int b = row0 >> 12, seq0 = row0 & 4095;
    const int r = t >> 2, kk = (t & 3) * 16;
    const unsigned short* apg = A + (long)(row0 + r) * E + kk;
    const unsigned short* wpg = W + (long)(col0 + r) * E + kk;
    uint4 a0 = *(const uint4*)apg,        a1 = *(const uint4*)(apg + 8);
    uint4 b0 = *(const uint4*)wpg,        b1 = *(const uint4*)(wpg + 8);
    float4v acc[2][2];
    for (int i = 0; i < 2; i++) for (int j = 0; j < 2; j++) acc[i][j] = (float4v){0.f, 0.f, 0.f, 0.f};
#pragma unroll
    for (int ki = 0; ki < 4; ki++) {
        __syncthreads();
        *(uint4*)&sA[r * 72 + kk] = a0; *(uint4*)&sA[r * 72 + kk + 8] = a1;
        *(uint4*)&sB[r * 72 + kk] = b0; *(uint4*)&sB[r * 72 + kk + 8] = b1;
        __syncthreads();
        if (ki < 3) {
            a0 = *(const uint4*)(apg + (ki + 1) * 64); a1 = *(const uint4*)(apg + (ki + 1) * 64 + 8);
            b0 = *(const uint4*)(wpg + (ki + 1) * 64); b1 = *(const uint4*)(wpg + (ki + 1) * 64 + 8);
        }
#pragma unroll
        for (int kf = 0; kf < 2; kf++) {
            const int ko = kf * 32 + quad * 8;
            short8 af0 = *(const short8*)&sA[(wr * 32 + lid) * 72 + ko];
            short8 af1 = *(const short8*)&sA[(wr * 32 + 16 + lid) * 72 + ko];
            short8 bf0 = *(const short8*)&sB[(wc * 32 + lid) * 72 + ko];
            short8 bf1 = *(const short8*)&sB[(wc * 32 + 16 + lid) * 72 + ko];
            acc[0][0] = mfma16(af0, bf0, acc[0][0]);
            acc[0][1] = mfma16(af0, bf1, acc[0][1]);
            acc[1][0] = mfma16(af1, bf0, acc[1][0]);
            acc[1][1] = mfma16(af1, bf1, acc[1][1]);
        }
    }
    if (col0 < 256) {  // ---- K half: rotary, direct stores ----
#pragma unroll
        for (int mt = 0; mt < 2; mt++)
#pragma unroll
            for (int nt = 0; nt < 2; nt++)
#pragma unroll
                for (int rr = 0; rr < 4; rr++) {
                    int m = wr * 32 + mt * 16 + quad * 4 + rr;
                    int c = col0 + wc * 32 + nt * 16 + lid;
                    int seq = seq0 + m;
                    float v = acc[mt][nt][rr] + bias[c];
                    unsigned int cs = *(const unsigned int*)&pos[(((long)b * LKV + seq) * E + c) * 2];
                    float cv = bf2f((unsigned short)cs), sv = bf2f((unsigned short)(cs >> 16));
                    float p = __shfl_xor(v, 1);
                    float x2 = (c & 1) ? p : -p;
                    float rv = v * cv + x2 * sv;
                    kout[(((long)b * NH + (c >> 5)) * LKV + seq) * HD + (c & 31)] = f2bf(rv);
                }
    } else {           // ---- V half: LDS transpose (reusing sA region) then coalesced writes ----
        __syncthreads();   // all waves done reading sA (block-uniform branch: safe)
        unsigned short* sT = smem;
#pragma unroll
        for (int mt = 0; mt < 2; mt++)
#pragma unroll
            for (int nt = 0; nt < 2; nt++) {
                int cl = wc * 32 + nt * 16 + lid;
                int so = wr * 32 + mt * 16 + quad * 4;
                float bcol = bias[col0 + cl];
                uint2 pw;
                pw.x = pack2(acc[mt][nt][0] + bcol, acc[mt][nt][1] + bcol);
                pw.y = pack2(acc[mt][nt][2] + bcol, acc[mt][nt][3] + bcol);
                *(uint2*)&sT[cl * 72 + so] = pw;
            }
        __syncthreads();
        const int cl = t >> 2, sc = (t & 3) * 16;
        uint4 u0 = *(const uint4*)&sT[cl * 72 + sc];
        uint4 u1 = *(const uint4*)&sT[cl * 72 + sc + 8];
        int cg = (col0 - 256) + cl;
        unsigned short* dst = vtout + (((long)b * NH + (cg >> 5)) * HD + (cg & 31)) * (long)LKV + seq0 + sc;
        *(uint4*)dst = u0;
        *(uint4*)(dst + 8) = u1;
    }
}

// ================ flash attention, split-KV(8), no online max, fenced sPT reuse (R7-proven) ================
// Opart written as bf16 (halves partials traffic).
__global__ __launch_bounds__(256) void attn_k(
        const unsigned short* __restrict__ qb, const unsigned short* __restrict__ kb,
        const unsigned short* __restrict__ vtb, unsigned short* __restrict__ Opart,
        float* __restrict__ lpart) {
    __shared__ unsigned short sK[CK * 40];       // 10.0 KB
    __shared__ unsigned short sVT[32 * 136];     // 8.5 KB
    __shared__ unsigned short sPT[4 * 64 * 36];  // 18.0 KB (per-wave, 64-key sub-chunk)
    const int t = threadIdx.x;
    const int lane = t & 63, wave = t >> 6, quad = lane >> 4, lid = lane & 15;
    const int qt0 = blockIdx.x * QT;
    const int bh = blockIdx.y;
    const int key0 = blockIdx.z * KSPAN;
    const unsigned short* kbase = kb + (long)bh * LKV * HD;
    const unsigned short* vbase = vtb + (long)bh * HD * LKV;
    short8 aq[2];
#pragma unroll
    for (int mf = 0; mf < 2; mf++)
        aq[mf] = *(const short8*)(qb + ((long)bh * LQ + qt0 + wave * 32 + mf * 16 + lid) * HD + quad * 8);
    float4v o[2][2];
#pragma unroll
    for (int i = 0; i < 2; i++) for (int j = 0; j < 2; j++) o[i][j] = (float4v){0.f, 0.f, 0.f, 0.f};
    float l[8] = {0.f, 0.f, 0.f, 0.f, 0.f, 0.f, 0.f, 0.f};
    const int krow = t >> 1, khalf = (t & 1) * 16;
    const int vrow = t >> 3, vkoff = (t & 7) * 16;
    unsigned short* myPT = &sPT[wave * 64 * 36];
    uint4 kv0 = *(const uint4*)(kbase + (long)(key0 + krow) * HD + khalf);
    uint4 kv1 = *(const uint4*)(kbase + (long)(key0 + krow) * HD + khalf + 8);
    uint4 vv0 = *(const uint4*)(vbase + (long)vrow * LKV + key0 + vkoff);
    uint4 vv1 = *(const uint4*)(vbase + (long)vrow * LKV + key0 + vkoff + 8);
    for (int ck = key0; ck < key0 + KSPAN; ck += CK) {
        __syncthreads();
        *(uint4*)&sK[krow * 40 + khalf] = kv0;
        *(uint4*)&sK[krow * 40 + khalf + 8] = kv1;
        *(uint4*)&sVT[vrow * 136 + vkoff] = vv0;
        *(uint4*)&sVT[vrow * 136 + vkoff + 8] = vv1;
        __syncthreads();
        if (ck + CK < key0 + KSPAN) {   // prefetch next chunk
            kv0 = *(const uint4*)(kbase + (long)(ck + CK + krow) * HD + khalf);
            kv1 = *(const uint4*)(kbase + (long)(ck + CK + krow) * HD + khalf + 8);
            vv0 = *(const uint4*)(vbase + (long)vrow * LKV + ck + CK + vkoff);
            vv1 = *(const uint4*)(vbase + (long)vrow * LKV + ck + CK + vkoff + 8);
        }
#pragma unroll
        for (int half = 0; half < 2; half++) {
#pragma unroll
            for (int nf = 0; nf < 4; nf++) {
                short8 bk = *(const short8*)&sK[(half * 64 + nf * 16 + lid) * 40 + quad * 8];
#pragma unroll
                for (int mf = 0; mf < 2; mf++) {
                    float4v z = (float4v){0.f, 0.f, 0.f, 0.f};
                    float4v s = mfma16(aq[mf], bk, z);
                    float e0 = __expf(s[0]), e1 = __expf(s[1]);
                    float e2 = __expf(s[2]), e3 = __expf(s[3]);
                    l[mf * 4 + 0] += e0; l[mf * 4 + 1] += e1;
                    l[mf * 4 + 2] += e2; l[mf * 4 + 3] += e3;
                    uint2 pk;
                    pk.x = pack2_rtz(e0, e1);
                    pk.y = pack2_rtz(e2, e3);
                    *(uint2*)&myPT[(nf * 16 + lid) * 36 + mf * 16 + quad * 4] = pk;
                }
            }
            LDS_FENCE();   // P writes drained before cross-lane reads (no barrier here!)
#pragma unroll
            for (int kb2 = 0; kb2 < 2; kb2++) {
                short8 bv0 = *(const short8*)&sVT[lid * 136 + half * 64 + kb2 * 32 + quad * 8];
                short8 bv1 = *(const short8*)&sVT[(16 + lid) * 136 + half * 64 + kb2 * 32 + quad * 8];
#pragma unroll
                for (int mf = 0; mf < 2; mf++) {
                    short8 ap;
#pragma unroll
                    for (int j = 0; j < 8; j++)
                        ap[j] = (short)myPT[(kb2 * 32 + quad * 8 + j) * 36 + mf * 16 + lid];
                    o[mf][0] = mfma16(ap, bv0, o[mf][0]);
                    o[mf][1] = mfma16(ap, bv1, o[mf][1]);
                }
            }
            LDS_FENCE();   // P reads drained before next half overwrites myPT
        }
    }
#pragma unroll
    for (int i = 0; i < 8; i++) {
#pragma unroll
        for (int d = 1; d < 16; d <<= 1) l[i] += __shfl_xor(l[i], d);
    }
#pragma unroll
    for (int mf = 0; mf < 2; mf++)
#pragma unroll
        for (int r = 0; r < 4; r++) {
            long orow = ((long)blockIdx.z * 32 + bh) * LQ + qt0 + wave * 32 + mf * 16 + quad * 4 + r;
            unsigned short* ob = Opart + orow * HD;
            ob[lid] = f2bf(o[mf][0][r]);
            ob[16 + lid] = f2bf(o[mf][1][r]);
            if (lid == 0) lpart[orow] = l[mf * 4 + r];
        }
}

extern "C" void kernel_launch(void* const* d_in, const int* in_sizes, int n_in,
                              void* d_out, int out_size, void* d_ws, size_t ws_size,
                              hipStream_t stream) {
    (void)in_sizes; (void)n_in; (void)out_size; (void)ws_size;
    const float* query = (const float*)d_in[0];
    const float* value = (const float*)d_in[1];
    const float* qpos  = (const float*)d_in[2];
    const float* vpos  = (const float*)d_in[3];
    const float* Wqkv  = (const float*)d_in[4];
    const float* bqkv  = (const float*)d_in[5];
    const float* Wo    = (const float*)d_in[6];
    const float* bo    = (const float*)d_in[7];
    const float* g1    = (const float*)d_in[8];
    const float* be1   = (const float*)d_in[9];
    const float* W1    = (const float*)d_in[10];
    const float* b1    = (const float*)d_in[11];
    const float* W2    = (const float*)d_in[12];
    const float* b2    = (const float*)d_in[13];
    const float* g2    = (const float*)d_in[14];
    const float* be2   = (const float*)d_in[15];
    float* outp = (float*)d_out;

    char* w = (char*)d_ws;
    float*          cur     = (float*)(w + 0);                     // 2 MB
    unsigned short* cur_bf  = (unsigned short*)(w + (2l  << 20));  // 1 MB
    unsigned short* qbuf    = (unsigned short*)(w + (3l  << 20));  // 1 MB
    float*          xb      = (float*)(w + (4l  << 20));           // 2 MB
    unsigned short* xb_bf   = (unsigned short*)(w + (6l  << 20));  // 1 MB
    unsigned short* h1b_bf  = (unsigned short*)(w + (7l  << 20));  // 1 MB
    float*          lp      = (float*)(w + (8l  << 20));           // 512 KB
    unsigned short* Opart   = (unsigned short*)(w + (9l  << 20));  // 8 MB bf16
    unsigned short* val_t   = (unsigned short*)(w + (25l << 20));  // 8 MB  [b][seq][E]
    unsigned short* wqkv_bf = (unsigned short*)(w + (33l << 20));  // 1.5 MB
    unsigned short* wo_bf   = (unsigned short*)(w + (35l << 20));  // 0.5 MB
    unsigned short* w1_bf   = (unsigned short*)(w + (36l << 20));  // 0.5 MB
    unsigned short* w2_bf   = (unsigned short*)(w + (37l << 20));  // 0.5 MB
    unsigned short* qpos_bf = (unsigned short*)(w + (38l << 20));  // 2 MB
    unsigned short* vpos_bf = (unsigned short*)(w + (40l << 20));  // 16 MB
    unsigned short* kbuf    = (unsigned short*)(w + (56l << 20));  // 32 MB (4 layers)
    unsigned short* vtb     = (unsigned short*)(w + (88l << 20));  // 32 MB (4 layers)

    pack_all<<<7680, 256, 0, stream>>>(value, Wqkv, Wo, W1, W2, qpos, vpos, query,
                                       val_t, wqkv_bf, wo_bf, w1_bf, w2_bf, qpos_bf,
                                       vpos_bf, cur, cur_bf);

    // all 4 layers' KV projection in one launch (value is layer-invariant)
    qkv_kv<<<dim3(256, 8, NLAYER), 256, 0, stream>>>(val_t, wqkv_bf, bqkv, vpos_bf, kbuf, vtb);

    for (int layer = 0; layer < NLAYER; layer++) {
        const unsigned short* Wl = wqkv_bf + (long)layer * 768 * 256;
        const float* bl = bqkv + (long)layer * 768;
        qkv_q<<<dim3(64, 4), 256, 0, stream>>>(cur_bf, Wl, bl, qpos_bf, qbuf);
        attn_k<<<dim3(LQ / QT, 32, SPLITS), 256, 0, stream>>>(
            qbuf, kbuf + (long)layer * 4194304, vtb + (long)layer * 4194304, Opart, lp);
        gemm_ln<1, 0><<<128, 256, 0, stream>>>(
            nullptr, Opart, lp, wo_bf + layer * 65536, bo + layer * 256,
            cur, g1 + layer * 256, be1 + layer * 256, xb, xb_bf, nullptr);
        gemm_k<<<dim3(64, 4), 256, 0, stream>>>(xb_bf, w1_bf + layer * 65536, b1 + layer * 256, h1b_bf);
        gemm_ln<0, 1><<<128, 256, 0, stream>>>(
            h1b_bf, nullptr, nullptr, w2_bf + layer * 65536, b2 + layer * 256,
            xb, g2 + layer * 256, be2 + layer * 256, cur, cur_bf,
            outp + (long)layer * LQ * NB * E);
    }
}